// Round 12
// baseline (31.830 us; speedup 1.0000x reference)
//
#include <hip/hip_runtime.h>
#include <hip/hip_bf16.h>

#define BB 64
#define SS 512
#define HH 1024
#define LL 9

// DPP add helper: 0x111/0x112/0x114/0x118 = row_shr 1/2/4/8;
// 0x142 = row_bcast15, 0x143 = row_bcast31. Sequence leaves the full
// 64-lane sum in lane 63. All VALU-rate, zero LDS pipe. (verified R10/R11)
template <int CTRL>
__device__ __forceinline__ float dpp_add(float v) {
    int s = __builtin_bit_cast(int, v);
    int r = __builtin_amdgcn_update_dpp(0, s, CTRL, 0xF, 0xF, true);
    return v + __builtin_bit_cast(float, r);
}

// R12: DENSE-STREAM variant (discriminator: bytes vs fixed floor).
// 512 blocks x 256 threads. Block (bat=blockIdx&63, seg=blockIdx>>6)
// computes the GEMM for ALL 64 tokens of its window — x read densely/
// sequentially (134 MB streaming, zero gather). Compaction happens at the
// OUTPUT: token t -> row excl[t] if valid, else nv + (t - excl[t]); both
// streams are contiguous ascending spans (bijection on [0,512)).
// Invalid tokens: acc*0 + bias -> softmax(bias) via the same code path.
// W hoisted to 144 VGPRs (R10); main loop touches only VMEM + VALU.
__global__ __launch_bounds__(256, 2) void fused_ner_kernel(
    const float* __restrict__ x, const int* __restrict__ mask,
    const float* __restrict__ W, const float* __restrict__ bias,
    float* __restrict__ out) {
    __shared__ __align__(16) float Wl[HH * LL];   // 36 KB staging for hoist
    __shared__ unsigned short dest_sh[SS];        // dest row | (valid<<15)
    __shared__ int wsum[4];
    __shared__ float bsh[LL];
    __shared__ float obuf[64 * LL];

    const int tid  = threadIdx.x;
    const int bat  = blockIdx.x & 63;             // consecutive -> XCD spread
    const int seg  = blockIdx.x >> 6;             // 0..7: 64-token window
    const int lane = tid & 63;
    const int wv_  = tid >> 6;                    // wave 0..3

    // ---- async stage W (row-major): 2304 float4, 9 per thread ----
    #pragma unroll
    for (int i = 0; i < 9; ++i) {
        const int f4 = i * 256 + tid;
        __builtin_amdgcn_global_load_lds(
            (const __attribute__((address_space(1))) void*)(W + f4 * 4),
            (__attribute__((address_space(3))) void*)(&Wl[f4 * 4]),
            16, 0, 0);
    }
    if (tid < LL) bsh[tid] = bias[tid];

    // ---- full-batch scan -> per-token output destination ----
    const int2 mm = reinterpret_cast<const int2*>(mask + bat * SS)[tid];
    const int m0 = mm.x, m1 = mm.y;
    const int s = m0 + m1;
    int incl = s;
    #pragma unroll
    for (int off = 1; off < 64; off <<= 1) {
        int u = __shfl_up(incl, off, 64);
        if (lane >= off) incl += u;
    }
    if (lane == 63) wsum[wv_] = incl;
    __syncthreads();                              // wsum ready; W stage drained
    int wbase = 0;
    #pragma unroll
    for (int i = 0; i < 4; ++i) if (i < wv_) wbase += wsum[i];
    const int nv = wsum[0] + wsum[1] + wsum[2] + wsum[3];
    const int e0 = incl - s + wbase;              // valids before token 2*tid
    const int t0g = 2 * tid;
    const int d0 = m0 ? e0 : nv + (t0g - e0);
    const int e1 = e0 + m0;
    const int d1 = m1 ? e1 : nv + (t0g + 1 - e1);
    dest_sh[t0g]     = (unsigned short)(d0 | (m0 << 15));
    dest_sh[t0g + 1] = (unsigned short)(d1 | (m1 << 15));
    __syncthreads();                              // dest_sh + Wl readable

    // ---- hoist W into registers (pass-invariant; 144 VGPRs) ----
    float wf[4][36];
    #pragma unroll
    for (int i = 0; i < 4; ++i) {
        const float* wp = &Wl[(i * 64 + lane) * 36];
        #pragma unroll
        for (int j = 0; j < 9; ++j) {
            const float4 t = *reinterpret_cast<const float4*>(wp + j * 4);
            wf[i][j * 4 + 0] = t.x;
            wf[i][j * 4 + 1] = t.y;
            wf[i][j * 4 + 2] = t.z;
            wf[i][j * 4 + 3] = t.w;
        }
    }

    // ---- dense pass loop: wave computes 2 consecutive tokens per pass ----
    #pragma unroll 1
    for (int pass = 0; pass < 8; ++pass) {
        const int lt0 = wv_ * 16 + pass * 2;      // local token 0..63
        const int t0 = seg * 64 + lt0;            // token in batch

        // dense rows: block reads a contiguous 256 KB span overall
        const float4* xr0 = reinterpret_cast<const float4*>(
            x + ((size_t)bat * SS + t0) * HH);
        const float4* xr1 = xr0 + (HH / 4);

        float4 xq[2][4];                          // 8 x 1KB wave-loads, burst
        #pragma unroll
        for (int i = 0; i < 4; ++i) {
            xq[0][i] = xr0[i * 64 + lane];
            xq[1][i] = xr1[i * 64 + lane];
        }

        float acc[2][LL];
        #pragma unroll
        for (int r = 0; r < 2; ++r)
            #pragma unroll
            for (int l = 0; l < LL; ++l) acc[r][l] = 0.f;

        #pragma unroll
        for (int i = 0; i < 4; ++i) {
            #pragma unroll
            for (int l = 0; l < LL; ++l) {
                #pragma unroll
                for (int r = 0; r < 2; ++r) {
                    const float4 xvv = xq[r][i];
                    acc[r][l] += xvv.x * wf[i][0 * 9 + l] + xvv.y * wf[i][1 * 9 + l]
                               + xvv.z * wf[i][2 * 9 + l] + xvv.w * wf[i][3 * 9 + l];
                }
            }
        }

        // 64-lane reduce, pure DPP: lane 63 ends with each full total
        #pragma unroll
        for (int r = 0; r < 2; ++r)
            #pragma unroll
            for (int l = 0; l < LL; ++l) {
                float v = acc[r][l];
                v = dpp_add<0x111>(v);
                v = dpp_add<0x112>(v);
                v = dpp_add<0x114>(v);
                v = dpp_add<0x118>(v);
                v = dpp_add<0x142>(v);
                v = dpp_add<0x143>(v);
                acc[r][l] = v;
            }

        if (lane == 63) {
            #pragma unroll
            for (int r = 0; r < 2; ++r) {
                const unsigned short dv = dest_sh[t0 + r];
                const float sc = (float)(dv >> 15);   // 0 -> softmax(bias)
                float lg[LL];
                float mx = -3.0e38f;
                #pragma unroll
                for (int l = 0; l < LL; ++l) {
                    lg[l] = acc[r][l] * sc + bsh[l];
                    mx = fmaxf(mx, lg[l]);
                }
                float ssum = 0.f;
                #pragma unroll
                for (int l = 0; l < LL; ++l) { lg[l] = __expf(lg[l] - mx); ssum += lg[l]; }
                const float inv = 1.f / ssum;
                #pragma unroll
                for (int l = 0; l < LL; ++l) obuf[(lt0 + r) * LL + l] = lg[l] * inv;
            }
        }
    }

    __syncthreads();                              // obuf complete

    // ---- output permutation: two ascending contiguous streams ----
    const size_t bbase = (size_t)bat * SS * LL;
    for (int el = tid; el < 64 * LL; el += 256) {
        const int lt = el / LL;                   // magic-mul const div
        const int l  = el - lt * LL;
        const int d  = dest_sh[seg * 64 + lt] & 0x1FF;
        out[bbase + (size_t)d * LL + l] = obuf[el];
    }
}

extern "C" void kernel_launch(void* const* d_in, const int* in_sizes, int n_in,
                              void* d_out, int out_size, void* d_ws, size_t ws_size,
                              hipStream_t stream) {
    const float* x    = (const float*)d_in[0];   // [B,S,H] f32
    const int*   mask = (const int*)d_in[1];     // [B,S] i32
    const float* W    = (const float*)d_in[2];   // [H,L] f32
    const float* bias = (const float*)d_in[3];   // [L] f32
    float* out = (float*)d_out;                  // [B,S,L] f32

    fused_ner_kernel<<<BB * 8, 256, 0, stream>>>(x, mask, W, bias, out);
}

// Round 13
// 21.941 us; speedup vs baseline: 1.4507x; 1.4507x over previous
//
#include <hip/hip_runtime.h>
#include <hip/hip_bf16.h>

#define BB 64
#define SS 512
#define HH 1024
#define LL 9

// DPP add helper: 0x111/0x112/0x114/0x118 = row_shr 1/2/4/8;
// 0x142 = row_bcast15, 0x143 = row_bcast31. Sequence leaves the full
// 64-lane sum in lane 63. All VALU-rate, zero LDS pipe. (verified R10/R11)
template <int CTRL>
__device__ __forceinline__ float dpp_add(float v) {
    int s = __builtin_bit_cast(int, v);
    int r = __builtin_amdgcn_update_dpp(0, s, CTRL, 0xF, 0xF, true);
    return v + __builtin_bit_cast(float, r);
}

// R13 = R11 revert (best: 22.55 us). Verdict from the R12 discriminator:
// ~12.5 us fixed launch/graph floor + ~68 MB valid-row gather at ~6.7 TB/s
// (~96% of achievable HBM) -> memory-roofline-bound. 1024 blocks (64
// batches x 16 exact slices) x 256 threads, 4 blocks/CU; W from LDS per
// chunk; 2 rows per wave-pass; burst 1KB wave-loads; pure-DPP reduce.
__global__ __launch_bounds__(256, 4) void fused_ner_kernel(
    const float* __restrict__ x, const int* __restrict__ mask,
    const float* __restrict__ W, const float* __restrict__ bias,
    float* __restrict__ out) {
    __shared__ __align__(16) float Wl[HH * LL];   // 36 KB, row-major W[h][l]
    __shared__ unsigned short gidx_sh[SS];        // 1 KB
    __shared__ int wsum[4];
    __shared__ float bsh[LL];
    __shared__ float obuf[32 * LL];               // slice <= 32 valid rows

    const int tid  = threadIdx.x;
    const int bat  = blockIdx.x & 63;             // consecutive -> XCD spread
    const int blk  = blockIdx.x >> 6;             // 0..15: slice index
    const int lane = tid & 63;
    const int wv_  = tid >> 6;                    // wave 0..3

    // ---- async stage W (row-major): 2304 float4, 9 per thread ----
    #pragma unroll
    for (int i = 0; i < 9; ++i) {
        const int f4 = i * 256 + tid;
        __builtin_amdgcn_global_load_lds(
            (const __attribute__((address_space(1))) void*)(W + f4 * 4),
            (__attribute__((address_space(3))) void*)(&Wl[f4 * 4]),
            16, 0, 0);
    }
    if (tid < LL) bsh[tid] = bias[tid];

    // ---- stable-compaction scan: 256 threads, 2 tokens each ----
    const int2 mm = reinterpret_cast<const int2*>(mask + bat * SS)[tid];
    const int m0 = mm.x, m1 = mm.y;
    const int s = m0 + m1;
    int incl = s;
    #pragma unroll
    for (int off = 1; off < 64; off <<= 1) {
        int u = __shfl_up(incl, off, 64);
        if (lane >= off) incl += u;
    }
    if (lane == 63) wsum[wv_] = incl;
    __syncthreads();                              // wsum ready; W stage drained
    int wbase = 0;
    #pragma unroll
    for (int i = 0; i < 4; ++i) if (i < wv_) wbase += wsum[i];
    const int nv = wsum[0] + wsum[1] + wsum[2] + wsum[3];
    const int excl = incl - s + wbase;
    if (m0) gidx_sh[excl] = (unsigned short)(2 * tid);
    if (m1) gidx_sh[excl + m0] = (unsigned short)(2 * tid + 1);
    __syncthreads();                              // gidx_sh + Wl readable

    // ---- this block's exact slices (16 per batch) ----
    const int jbeg = (blk * nv) >> 4;
    const int jend = ((blk + 1) * nv) >> 4;
    const int nwork = jend - jbeg;                // <= 32
    const int npad = SS - nv;
    const int pbeg = nv + ((blk * npad) >> 4);
    const int pend = nv + (((blk + 1) * npad) >> 4);

    // ---- pass loop: wave computes 2 queue rows per pass ----
    #pragma unroll 1
    for (int pass = 0; pass < 4; ++pass) {
        const int lp0 = pass * 8 + wv_ * 2;       // local row base (this wave)
        if (lp0 >= nwork) break;                  // wave-uniform

        float sc[2];
        const float4* xr[2];
        #pragma unroll
        for (int r = 0; r < 2; ++r) {
            const int j = jbeg + lp0 + r;
            const bool valid = (j < jend);
            sc[r] = valid ? 1.f : 0.f;
            const int src = gidx_sh[valid ? j : jbeg];   // jbeg valid (nwork>0)
            xr[r] = reinterpret_cast<const float4*>(x + ((size_t)bat * SS + src) * HH);
        }

        // burst: 8 wave-loads (1KB contiguous each) issued back-to-back
        float4 xq[2][4];                          // [r][i], static-indexed
        #pragma unroll
        for (int i = 0; i < 4; ++i)
            #pragma unroll
            for (int r = 0; r < 2; ++r) xq[r][i] = xr[r][i * 64 + lane];

        float acc[2][LL];
        #pragma unroll
        for (int r = 0; r < 2; ++r)
            #pragma unroll
            for (int l = 0; l < LL; ++l) acc[r][l] = 0.f;

        #pragma unroll
        for (int i = 0; i < 4; ++i) {
            // lane's W sub-block for h-block (i*64+lane): 36 contiguous floats
            float4 wb[9];
            const float* wp = &Wl[(i * 64 + lane) * 36];
            #pragma unroll
            for (int j2 = 0; j2 < 9; ++j2)
                wb[j2] = *reinterpret_cast<const float4*>(wp + j2 * 4);
            const float* wf = reinterpret_cast<const float*>(wb); // wf[dh*9+l]

            #pragma unroll
            for (int l = 0; l < LL; ++l) {
                #pragma unroll
                for (int r = 0; r < 2; ++r) {
                    const float4 xvv = xq[r][i];
                    acc[r][l] += xvv.x * wf[0 * 9 + l] + xvv.y * wf[1 * 9 + l]
                               + xvv.z * wf[2 * 9 + l] + xvv.w * wf[3 * 9 + l];
                }
            }
        }

        // 64-lane reduce, pure DPP: lane 63 ends with each full total
        #pragma unroll
        for (int r = 0; r < 2; ++r)
            #pragma unroll
            for (int l = 0; l < LL; ++l) {
                float v = acc[r][l];
                v = dpp_add<0x111>(v);
                v = dpp_add<0x112>(v);
                v = dpp_add<0x114>(v);
                v = dpp_add<0x118>(v);
                v = dpp_add<0x142>(v);
                v = dpp_add<0x143>(v);
                acc[r][l] = v;
            }

        if (lane == 63) {
            #pragma unroll
            for (int r = 0; r < 2; ++r) {
                float lg[LL];
                float mx = -3.0e38f;
                #pragma unroll
                for (int l = 0; l < LL; ++l) {
                    lg[l] = acc[r][l] * sc[r] + bsh[l];
                    mx = fmaxf(mx, lg[l]);
                }
                float ssum = 0.f;
                #pragma unroll
                for (int l = 0; l < LL; ++l) { lg[l] = __expf(lg[l] - mx); ssum += lg[l]; }
                const float inv = 1.f / ssum;
                #pragma unroll
                for (int l = 0; l < LL; ++l) obuf[(lp0 + r) * LL + l] = lg[l] * inv;
            }
        }
    }

    // softmax(bias) in registers (for pad slice)
    float bs[LL];
    float mxb = -3.0e38f;
    #pragma unroll
    for (int l = 0; l < LL; ++l) { bs[l] = bsh[l]; mxb = fmaxf(mxb, bs[l]); }
    float sb = 0.f;
    #pragma unroll
    for (int l = 0; l < LL; ++l) { bs[l] = __expf(bs[l] - mxb); sb += bs[l]; }
    const float invb = 1.f / sb;

    __syncthreads();                              // obuf complete

    // valid slice: contiguous nwork*9 floats
    const size_t vbase = ((size_t)bat * SS + jbeg) * LL;
    for (int t = tid; t < nwork * LL; t += 256) out[vbase + t] = obuf[t];

    // pad slice: contiguous (pend-pbeg)*9 floats of softmax(bias)
    const size_t pbase = ((size_t)bat * SS + pbeg) * LL;
    const int pn = (pend - pbeg) * LL;
    for (int t = tid; t < pn; t += 256) {
        const int row = t / LL;
        const int l   = t - row * LL;
        out[pbase + t] = bs[l] * invb;
    }
}

extern "C" void kernel_launch(void* const* d_in, const int* in_sizes, int n_in,
                              void* d_out, int out_size, void* d_ws, size_t ws_size,
                              hipStream_t stream) {
    const float* x    = (const float*)d_in[0];   // [B,S,H] f32
    const int*   mask = (const int*)d_in[1];     // [B,S] i32
    const float* W    = (const float*)d_in[2];   // [H,L] f32
    const float* bias = (const float*)d_in[3];   // [L] f32
    float* out = (float*)d_out;                  // [B,S,L] f32

    fused_ner_kernel<<<BB * 16, 256, 0, stream>>>(x, mask, W, bias, out);
}